// Round 12
// baseline (195.282 us; speedup 1.0000x reference)
//
#include <hip/hip_runtime.h>

typedef __attribute__((ext_vector_type(8))) short bf16x8;
typedef __attribute__((ext_vector_type(4))) float f32x4;

__device__ __forceinline__ unsigned short f2bf(float f) {
  unsigned int u = __builtin_bit_cast(unsigned int, f);
  unsigned int r = (u + 0x7FFFu + ((u >> 16) & 1u)) >> 16;  // RNE (finite inputs)
  return (unsigned short)r;
}

// Packed weight images: each wave's fragment load is ONE CONTIGUOUS 1KB burst.
// wm_img[i]: ushort[4096] = [tt(4)][sn(2)][q(4)][m(16)][j(8)]
//            value = Wm[i][k= sn*32+q*8+j][col= tt*16+m]
//   -> phase g = i*4+tt reads bytes [g*2048, g*2048+2048): LINEAR in g.
// wu_img:    ushort[8192] = [tt(4)][part(4, part3=pad0)][q(4)][m(16)][j(8)]
//            value = Wu[k= part*32+q*8+j][col= tt*16+m]   (k<96)
__global__ void prep_weights(const float* __restrict__ Wm,
                             const float* __restrict__ Wu,
                             unsigned short* __restrict__ wm_img,
                             unsigned short* __restrict__ wu_img) {
  const int i = blockIdx.x;
  const int tid = threadIdx.x;
  if (i < 26) {
    for (int e = tid; e < 4096; e += 256) {
      const int j = e & 7, m = (e >> 3) & 15, q = (e >> 7) & 3;
      const int sn = (e >> 9) & 1, tt = e >> 10;
      const int k = sn * 32 + q * 8 + j, col = tt * 16 + m;
      wm_img[i * 4096 + e] = f2bf(Wm[(i * 64 + k) * 64 + col]);
    }
  } else {
    for (int e = tid; e < 8192; e += 256) {
      const int j = e & 7, m = (e >> 3) & 15, q = (e >> 7) & 3;
      const int part = (e >> 9) & 3, tt = e >> 11;
      const int k = part * 32 + q * 8 + j, col = tt * 16 + m;
      wu_img[e] = (k < 96) ? f2bf(Wu[k * 64 + col]) : (unsigned short)0;
    }
  }
}

// R12 = R11 with the pipeline schedule FIXED. R11 bug: prologue loaded only
// phase 0 -> set A, but PH_MFMA(1) consumed set B (uninitialized at i=0,
// stale phase i*4+3 afterwards) -> absmax 2.5e36.
// Invariant now: at iter-i entry, A = phase 4i, B = phase 4i+1.
//   prologue: A <- ph0, B <- ph1
//   loop: MFMA0(A); PREF A<-ph(4i+2); MFMA1(B); PREF B<-ph(4i+3); VALU0;
//         MFMA2(A); PREF A<-ph(4i+4); VALU1; MFMA3(B); PREF B<-ph(4i+5);
//         VALU2; VALU3
// Each prefetch is issued right after its set's MFMA, >= 2 MFMAs + 1 VALU
// block of lead before consumption. Nested-MFMA bias (C=bmq broadcast shared
// by both gg) + 2-deep accE/accO pipeline (static names, rule #20) attack the
// VALU dependency serialization (R10: VALU 54% busy = binding pipe).
//
// Occupancy (R1-R10): (512,4) => 128 unified regs/wave; live est ~114.
// Tripwire: WRITE_SIZE ~= 131072 KB (R10: 135224 = ~1-reg spill, tolerated).
#define CB_STRIDE 10384  // 6*6*18*16 + 16B skew
__global__ __launch_bounds__(512, 4)
void voxconv_main(const float* __restrict__ x,
                  const float* __restrict__ occ,
                  const float* __restrict__ bm,
                  const float* __restrict__ bu,
                  const unsigned short* __restrict__ wm_img,
                  const unsigned short* __restrict__ wu_img,
                  float* __restrict__ out) {
  // x halo: [cb(4)][hx(6)][hy(6)][hz(18)][8ch] bf16 ; strides B: cb CB_STRIDE, hx 1728, hy 288, hz 16
  __shared__ __align__(16) unsigned short x_lds[2 * CB_STRIDE];  // 41536 B
  __shared__ __align__(16) float occ_lds[648];                   // [6][6][18] f32, 2592 B
  __shared__ __align__(16) unsigned short sc_lds[8192];          // epilogue scratch, 16384 B
  // total 60512 B -> LDS_Block_Size 60928 -> 2 blocks/CU

  const int tid  = (int)threadIdx.x;
  const int lane = tid & 63;
  const int w    = tid >> 6;
  const int q    = lane >> 4;   // k-chunk / quarter-wave
  const int m    = lane & 15;   // A row (z) / C col (within 16)

  const int id = (int)blockIdx.x;
  const int b  = id >> 10;
  const int ix = (id >> 6) & 15;
  const int iy = (id >> 2) & 15;
  const int iz = id & 3;
  const int x0 = ix << 2, y0 = iy << 2, z0 = iz << 4;

  // ---- stage x halo (648 voxels x 4 ch-chunks = 2592 items), f32 -> bf16 ----
  for (int it = 0; it < 6; ++it) {
    const int t = tid + it * 512;
    if (t < 2592) {
      const int cb = t & 3;
      const int v  = t >> 2;
      const int hz = v % 18;
      const int v2 = v / 18;
      const int hy = v2 % 6;
      const int hx = v2 / 6;
      const int X = (x0 + 63 + hx) & 63;
      const int Y = (y0 + 63 + hy) & 63;
      const int Z = (z0 + 63 + hz) & 63;
      const int vox = ((b * 64 + X) * 64 + Y) * 64 + Z;
      const float4* s4 = (const float4*)(x + vox * 32 + cb * 8);
      const float4 f0 = s4[0];
      const float4 f1 = s4[1];
      uint4 P;
      P.x = (unsigned)f2bf(f0.x) | ((unsigned)f2bf(f0.y) << 16);
      P.y = (unsigned)f2bf(f0.z) | ((unsigned)f2bf(f0.w) << 16);
      P.z = (unsigned)f2bf(f1.x) | ((unsigned)f2bf(f1.y) << 16);
      P.w = (unsigned)f2bf(f1.z) | ((unsigned)f2bf(f1.w) << 16);
      *(uint4*)((char*)x_lds + cb * CB_STRIDE + hx * 1728 + hy * 288 + hz * 16) = P;
    }
  }
  // ---- stage occ halo (f32) ----
  for (int t = tid; t < 648; t += 512) {
    const int hz = t % 18;
    const int v2 = t / 18;
    const int hy = v2 % 6;
    const int hx = v2 / 6;
    const int X = (x0 + 63 + hx) & 63;
    const int Y = (y0 + 63 + hy) & 63;
    const int Z = (z0 + 63 + hz) & 63;
    occ_lds[t] = occ[((b * 64 + X) * 64 + Y) * 64 + Z];
  }
  __syncthreads();  // x_lds / occ_lds read-only hereafter -> NO more barriers

  // ---- per-thread constant addresses (wave w owns columns g = 2w, 2w+1) ----
  int aSelf[2], occSelf[2];
  #pragma unroll
  for (int gg = 0; gg < 2; ++gg) {
    const int g  = w * 2 + gg;
    const int tx = g >> 2, ty = g & 3;
    aSelf[gg]   = q * CB_STRIDE + (tx + 1) * 1728 + (ty + 1) * 288 + (1 + m) * 16;
    occSelf[gg] = (tx + 1) * 108 + (ty + 1) * 18 + 1 + q * 4;
  }

  float agg[2][4][4];
  float den[2][4];
  #pragma unroll
  for (int gg = 0; gg < 2; ++gg)
    #pragma unroll
    for (int j = 0; j < 4; ++j) {
      den[gg][j] = 0.0f;
      #pragma unroll
      for (int tt = 0; tt < 4; ++tt) agg[gg][tt][j] = 0.0f;
    }

  // ---- B ping-pong register sets; prologue: A <- phase 0, B <- phase 1 ----
  const char* wmb = (const char*)wm_img + (unsigned)lane * 16;
  bf16x8 bSA, bNA, bSB, bNB;
  bSA = *(const bf16x8*)(wmb);
  bNA = *(const bf16x8*)(wmb + 1024);
  bSB = *(const bf16x8*)(wmb + 2048);
  bNB = *(const bf16x8*)(wmb + 2048 + 1024);

// MFMA half of a phase: nested pair, C=bmq shared by both gg (D != C).
#define PH_MFMA(TT, BS, BN, ACC)                                               \
  {                                                                            \
    const f32x4 bmq = {bmv[TT], bmv[TT], bmv[TT], bmv[TT]};                    \
    ACC[0] = __builtin_amdgcn_mfma_f32_16x16x32_bf16(                          \
        aN[0], BN,                                                             \
        __builtin_amdgcn_mfma_f32_16x16x32_bf16(aS[0], BS, bmq, 0, 0, 0),      \
        0, 0, 0);                                                              \
    ACC[1] = __builtin_amdgcn_mfma_f32_16x16x32_bf16(                          \
        aN[1], BN,                                                             \
        __builtin_amdgcn_mfma_f32_16x16x32_bf16(aS[1], BS, bmq, 0, 0, 0),      \
        0, 0, 0);                                                              \
  }

// VALU half of a phase (runs under a LATER phase's MFMA shadow).
#define PH_VALU(TT, ACC)                                                       \
  {                                                                            \
    _Pragma("unroll")                                                          \
    for (int gg = 0; gg < 2; ++gg) {                                           \
      _Pragma("unroll")                                                        \
      for (int j = 0; j < 4; ++j) {                                            \
        const float msg = fmaxf(ACC[gg][j], 0.0f);                             \
        agg[gg][TT][j] = fmaf(msg, on[gg][j], agg[gg][TT][j]);                 \
      }                                                                        \
    }                                                                          \
  }

// Load global phase (i*4 + PH) into a register set (linear address in g).
#define PH_PREF(PH, BSN, BNN)                                                  \
  {                                                                            \
    const char* np_ = wmb + ((unsigned)i * 8192u + (unsigned)(PH) * 2048u);    \
    BSN = *(const bf16x8*)np_;                                                 \
    BNN = *(const bf16x8*)(np_ + 1024);                                        \
  }

  // ---- 26-offset main loop: barrier-free, 2-deep acc pipeline ----
  #pragma unroll 1
  for (int i = 0; i < 26; ++i) {
    // bm row i (L2-hot); 4 scalars per lane
    float bmv[4];
    #pragma unroll
    for (int tt = 0; tt < 4; ++tt) bmv[tt] = bm[(i * 4 + tt) * 16 + m];

    const int oi  = (i < 13) ? i : i + 1;          // skip (0,0,0)
    const int dxo = oi / 9 - 1;
    const int dyo = (oi / 3) % 3 - 1;
    const int dzo = oi % 3 - 1;
    // neighbor p-d (roll semantics: x_nb[p] = x[p-d])
    const int dA = -(dxo * 1728 + dyo * 288 + dzo * 16);
    const int dO = -(dxo * 108 + dyo * 18 + dzo);

    // A-frags + occ for both columns (LDS; shared across the 4 phases)
    bf16x8 aS[2], aN[2];
    float on[2][4];
    #pragma unroll
    for (int gg = 0; gg < 2; ++gg) {
      aS[gg] = *(const bf16x8*)((const char*)x_lds + aSelf[gg]);
      aN[gg] = *(const bf16x8*)((const char*)x_lds + aSelf[gg] + dA);
      #pragma unroll
      for (int j = 0; j < 4; ++j) on[gg][j] = occ_lds[occSelf[gg] + dO + j];
    }
    #pragma unroll
    for (int gg = 0; gg < 2; ++gg)
      #pragma unroll
      for (int j = 0; j < 4; ++j) den[gg][j] += on[gg][j];

    f32x4 accE[2], accO[2];
    PH_MFMA(0, bSA, bNA, accE)          // consumes A = phase 4i
    PH_PREF(2, bSA, bNA)                // A <- phase 4i+2
    PH_MFMA(1, bSB, bNB, accO)          // consumes B = phase 4i+1
    PH_PREF(3, bSB, bNB)                // B <- phase 4i+3
    PH_VALU(0, accE)
    PH_MFMA(2, bSA, bNA, accE)          // consumes A = phase 4i+2
    if (i < 25) PH_PREF(4, bSA, bNA)    // A <- phase 4(i+1)
    PH_VALU(1, accO)
    PH_MFMA(3, bSB, bNB, accO)          // consumes B = phase 4i+3
    if (i < 25) PH_PREF(5, bSB, bNB)    // B <- phase 4(i+1)+1
    PH_VALU(2, accE)
    PH_VALU(3, accO)
  }
#undef PH_MFMA
#undef PH_VALU
#undef PH_PREF

  // ---- agg /= (den + 1e-8) ----
  #pragma unroll
  for (int gg = 0; gg < 2; ++gg)
    #pragma unroll
    for (int j = 0; j < 4; ++j) {
      const float r = 1.0f / (den[gg][j] + 1e-8f);
      #pragma unroll
      for (int tt = 0; tt < 4; ++tt) agg[gg][tt][j] *= r;
    }

  // ---- update matmul: out = ([x|agg] @ Wu + bu) * occ_self ----
  char* scratch = (char*)sc_lds + w * 2048;  // per-wave 16 rows x 128B, private
  const int l7 = lane & 7;
  int colIdx[4];
  #pragma unroll
  for (int tt = 0; tt < 4; ++tt) colIdx[tt] = tt * 16 + m;
  int voxBase[2];
  #pragma unroll
  for (int gg = 0; gg < 2; ++gg) {
    const int g  = w * 2 + gg;
    const int tx = g >> 2, ty = g & 3;
    voxBase[gg] = ((b * 64 + (x0 + tx)) * 64 + (y0 + ty)) * 64 + z0;
  }
  float buv[4];
  #pragma unroll
  for (int tt = 0; tt < 4; ++tt) buv[tt] = bu[colIdx[tt]];

  const char* wub = (const char*)wu_img + (unsigned)lane * 16;
  #pragma unroll
  for (int gg = 0; gg < 2; ++gg) {
    // C-layout agg -> bf16 A-layout scratch (row-XOR swizzle); per-wave
    // private, wave-synchronous: no barrier needed.
    #pragma unroll
    for (int tt = 0; tt < 4; ++tt) {
      const int colhi = tt * 2 + ((lane >> 3) & 1);  // col>>3
      #pragma unroll
      for (int j = 0; j < 4; ++j) {
        const int row = q * 4 + j;
        const int bo = row * 128 + ((colhi ^ (row & 7)) << 4) + l7 * 2;
        *(unsigned short*)(scratch + bo) = f2bf(agg[gg][tt][j]);
      }
    }
    const bf16x8 ax  = *(const bf16x8*)((const char*)x_lds + aSelf[gg]);
    const bf16x8 ag0 = *(const bf16x8*)(scratch + m * 128 + ((q ^ (m & 7)) << 4));
    const bf16x8 ag1 = *(const bf16x8*)(scratch + m * 128 + (((4 + q) ^ (m & 7)) << 4));
    float os[4];
    #pragma unroll
    for (int j = 0; j < 4; ++j) os[j] = occ_lds[occSelf[gg] + j];
    // Wu fragments per-tt from packed L2 image (contiguous 1KB wave bursts)
    #pragma unroll
    for (int tt = 0; tt < 4; ++tt) {
      const bf16x8 bux  = *(const bf16x8*)(wub + tt * 4096);         // k 0..31 (x)
      const bf16x8 bua0 = *(const bf16x8*)(wub + tt * 4096 + 1024);  // k 32..63
      const bf16x8 bua1 = *(const bf16x8*)(wub + tt * 4096 + 2048);  // k 64..95
      f32x4 acc = {buv[tt], buv[tt], buv[tt], buv[tt]};
      acc = __builtin_amdgcn_mfma_f32_16x16x32_bf16(ax,  bux,  acc, 0, 0, 0);
      acc = __builtin_amdgcn_mfma_f32_16x16x32_bf16(ag0, bua0, acc, 0, 0, 0);
      acc = __builtin_amdgcn_mfma_f32_16x16x32_bf16(ag1, bua1, acc, 0, 0, 0);
      #pragma unroll
      for (int j = 0; j < 4; ++j) {
        out[(voxBase[gg] + q * 4 + j) * 64 + colIdx[tt]] = acc[j] * os[j];
      }
    }
  }
}

extern "C" void kernel_launch(void* const* d_in, const int* in_sizes, int n_in,
                              void* d_out, int out_size, void* d_ws, size_t ws_size,
                              hipStream_t stream) {
  const float* x   = (const float*)d_in[0];
  const float* occ = (const float*)d_in[1];
  const float* Wm  = (const float*)d_in[2];
  const float* bm  = (const float*)d_in[3];
  const float* Wu  = (const float*)d_in[4];
  const float* bu  = (const float*)d_in[5];
  float* out = (float*)d_out;

  unsigned short* wm_img = (unsigned short*)d_ws;        // 26*4096 ushort = 208 KB
  unsigned short* wu_img = wm_img + 26 * 4096;           // 8192 ushort   =  16 KB

  prep_weights<<<27, 256, 0, stream>>>(Wm, Wu, wm_img, wu_img);
  voxconv_main<<<2048, 512, 0, stream>>>(x, occ, bm, bu, wm_img, wu_img, out);
}

// Round 13
// 185.438 us; speedup vs baseline: 1.0531x; 1.0531x over previous
//
#include <hip/hip_runtime.h>

typedef __attribute__((ext_vector_type(8))) short bf16x8;
typedef __attribute__((ext_vector_type(4))) float f32x4;

__device__ __forceinline__ unsigned short f2bf(float f) {
  unsigned int u = __builtin_bit_cast(unsigned int, f);
  unsigned int r = (u + 0x7FFFu + ((u >> 16) & 1u)) >> 16;  // RNE (finite inputs)
  return (unsigned short)r;
}

// Build bf16 transposed + 16B-chunk-XOR-swizzled weight images in ws.
// wm_img[i]: [col(64)][k(64)] bf16, 128B rows, chunk ^= (col&7); val = Wm[i][k][col]
//            k 0..31 = W_self, k 32..63 = W_nb
// wu_img:    [col(64)][k(128, pad)] bf16, 256B rows, chunk ^= (col&7); k<96: Wu[k][col]
__global__ void prep_weights(const float* __restrict__ Wm,
                             const float* __restrict__ Wu,
                             unsigned short* __restrict__ wm_img,
                             unsigned short* __restrict__ wu_img) {
  const int i = blockIdx.x;
  const int tid = threadIdx.x;
  if (i < 26) {
    for (int e = tid; e < 4096; e += 256) {
      const int col = e & 63, k = e >> 6;
      const float v = Wm[(i * 64 + k) * 64 + col];
      const int bo = col * 128 + (((k >> 3) ^ (col & 7)) << 4) + (k & 7) * 2;
      wm_img[i * 4096 + (bo >> 1)] = f2bf(v);
    }
  } else {
    for (int e = tid; e < 8192; e += 256) {
      const int col = e >> 7, k = e & 127;
      const float v = (k < 96) ? Wu[k * 64 + col] : 0.0f;
      const int bo = col * 256 + (((k >> 3) ^ (col & 7)) << 4) + (k & 7) * 2;
      wu_img[bo >> 1] = f2bf(v);
    }
  }
}

// R13 = R7 (best: 209us/dispatch) + VALU cuts. R7 structure: 4x4x16 tile,
// 8 waves x 2 columns, Wm LDS-dbuf via global_load_lds (wave-uniform base +
// lane*16), per-iter barrier, Wu/bm from L2. VALU was the top pipe (59%).
//  (1) nested-MFMA bias: acc = mfma(aN,bN, mfma(aS,bS,bmq)); one bmq per tt
//      shared as C by both gg (MFMA D != C) -> kills 32 acc-init movs/iter.
//  (2) staging-address hoist: per-thread (cb,hy,hz,YZ) computed ONCE; the
//      6 hx-planes reuse them (only X varies) -> ~95 fewer VALU/thread.
// R12 lesson (T15 confirmed): 2-deep acc pipeline (+16 regs) spills under the
// (512,4) 128-reg budget -> abandoned. Tripwire: WRITE_SIZE == 131072 KB.
#define CB_STRIDE 10384  // 6*6*18*16 + 16B skew: staging lanes cb=0..3 distinct banks
__global__ __launch_bounds__(512, 4)
void voxconv_main(const float* __restrict__ x,
                  const float* __restrict__ occ,
                  const float* __restrict__ bm,
                  const float* __restrict__ bu,
                  const unsigned short* __restrict__ wm_img,
                  const unsigned short* __restrict__ wu_img,
                  float* __restrict__ out) {
  // x halo: [cb(4)][hx(6)][hy(6)][hz(18)][8ch] bf16 ; strides B: cb CB_STRIDE, hx 1728, hy 288, hz 16
  __shared__ __align__(16) unsigned short x_lds[2 * CB_STRIDE];  // 41536 B
  __shared__ __align__(16) float occ_lds[648];                   // [6][6][18] f32, 2592 B
  __shared__ __align__(16) unsigned short wm_buf[8192];          // 2 x 8KB dbuf; later agg scratch
  // total 60512 B -> LDS_Block_Size 60928 -> 2 blocks/CU

  const int tid  = (int)threadIdx.x;
  const int lane = tid & 63;
  const int w    = tid >> 6;
  const int q    = lane >> 4;   // k-chunk / quarter-wave
  const int m    = lane & 15;   // A row (z) / C col (within 16)
  const int l7   = lane & 7;

  const int id = (int)blockIdx.x;
  const int b  = id >> 10;
  const int ix = (id >> 6) & 15;
  const int iy = (id >> 2) & 15;
  const int iz = id & 3;
  const int x0 = ix << 2, y0 = iy << 2, z0 = iz << 4;

  // ---- stage x halo: per-thread decomposition hoisted (432 active threads,
  // 6 hx-planes; only X varies per plane) ----
  {
    const int scb = tid & 3;          // ch-chunk
    const int sr  = tid >> 2;         // slot within plane (valid < 108)
    const int shz = sr % 18;
    const int shy = sr / 18;
    const bool sact = (sr < 108);
    const int sY = (y0 + 63 + shy) & 63;
    const int sZ = (z0 + 63 + shz) & 63;
    const int sYZ = sY * 64 + sZ;
    const int sldsbase = scb * CB_STRIDE + shy * 288 + shz * 16;
    if (sact) {
      for (int hx = 0; hx < 6; ++hx) {
        const int X = (x0 + 63 + hx) & 63;
        const int vox = (b * 64 + X) * 4096 + sYZ;
        const float4* s4 = (const float4*)(x + vox * 32 + scb * 8);
        const float4 f0 = s4[0];
        const float4 f1 = s4[1];
        uint4 P;
        P.x = (unsigned)f2bf(f0.x) | ((unsigned)f2bf(f0.y) << 16);
        P.y = (unsigned)f2bf(f0.z) | ((unsigned)f2bf(f0.w) << 16);
        P.z = (unsigned)f2bf(f1.x) | ((unsigned)f2bf(f1.y) << 16);
        P.w = (unsigned)f2bf(f1.z) | ((unsigned)f2bf(f1.w) << 16);
        *(uint4*)((char*)x_lds + sldsbase + hx * 1728) = P;
      }
    }
  }
  // ---- stage occ halo (f32) ----
  for (int t = tid; t < 648; t += 512) {
    const int hz = t % 18;
    const int v2 = t / 18;
    const int hy = v2 % 6;
    const int hx = v2 / 6;
    const int X = (x0 + 63 + hx) & 63;
    const int Y = (y0 + 63 + hy) & 63;
    const int Z = (z0 + 63 + hz) & 63;
    occ_lds[t] = occ[((b * 64 + X) * 64 + Y) * 64 + Z];
  }
  // ---- stage first Wm image ----
  ((uint4*)wm_buf)[tid] = ((const uint4*)wm_img)[tid];
  __syncthreads();

  // ---- per-thread constant addresses (wave w owns columns g = 2w, 2w+1) ----
  int aSelf[2], occSelf[2], voxBase[2];
  #pragma unroll
  for (int gg = 0; gg < 2; ++gg) {
    const int g  = w * 2 + gg;
    const int tx = g >> 2, ty = g & 3;
    aSelf[gg]   = q * CB_STRIDE + (tx + 1) * 1728 + (ty + 1) * 288 + (1 + m) * 16;
    occSelf[gg] = (tx + 1) * 108 + (ty + 1) * 18 + 1 + q * 4;
    voxBase[gg] = ((b * 64 + (x0 + tx)) * 64 + (y0 + ty)) * 64 + z0;
  }
  int bOffS[4], bOffN[4], colIdx[4];
  #pragma unroll
  for (int tt = 0; tt < 4; ++tt) {
    const int col = tt * 16 + m;
    colIdx[tt] = col;
    bOffS[tt] = col * 128 + ((q ^ l7) << 4);          // k chunk q   (self, k 0..31)
    bOffN[tt] = col * 128 + (((4 + q) ^ l7) << 4);    // k chunk 4+q (nb,  k 32..63)
  }

  // Loop-invariant self A-fragments (x_lds immutable after prologue);
  // also reused as the epilogue's x fragment.
  bf16x8 aS[2];
  #pragma unroll
  for (int gg = 0; gg < 2; ++gg)
    aS[gg] = *(const bf16x8*)((const char*)x_lds + aSelf[gg]);

  float agg[2][4][4];
  float den[2][4];
  #pragma unroll
  for (int gg = 0; gg < 2; ++gg)
    #pragma unroll
    for (int j = 0; j < 4; ++j) {
      den[gg][j] = 0.0f;
      #pragma unroll
      for (int tt = 0; tt < 4; ++tt) agg[gg][tt][j] = 0.0f;
    }

  // Per-wave async-prefetch addresses: wave w's 1KB slice of the 8KB image.
  const unsigned short* gsrc_base = wm_img + 4096 + (unsigned)tid * 8;  // image i+1 at i=0

  // ---- 26-offset main loop, Wm double-buffered via global_load_lds ----
  int cur = 0;
  #pragma unroll 1
  for (int i = 0; i < 26; ++i) {
    if (i < 25) {
      // async global->LDS: 16B/lane, wave-uniform LDS base (w*1024 slice)
      __builtin_amdgcn_global_load_lds(
          (const __attribute__((address_space(1))) void*)(gsrc_base + (unsigned)i * 4096),
          (__attribute__((address_space(3))) void*)((char*)wm_buf + (cur ^ 1) * 8192 + w * 1024 + (lane * 16)),
          16, 0, 0);
    }

    // bm row i from global: 6.6KB L2-resident table
    float bmv[4];
    #pragma unroll
    for (int tt = 0; tt < 4; ++tt) bmv[tt] = bm[i * 64 + colIdx[tt]];

    const int oi  = (i < 13) ? i : i + 1;          // skip (0,0,0)
    const int dxo = oi / 9 - 1;
    const int dyo = (oi / 3) % 3 - 1;
    const int dzo = oi % 3 - 1;
    // neighbor q = p - d  (roll semantics: x_nb[p] = x[p-d])
    const int dA = -(dxo * 1728 + dyo * 288 + dzo * 16);
    const int dO = -(dxo * 108 + dyo * 18 + dzo);

    // neighbor A-frags + occ for both columns (shared across all tt)
    bf16x8 aN[2];
    float on[2][4];
    #pragma unroll
    for (int gg = 0; gg < 2; ++gg) {
      aN[gg] = *(const bf16x8*)((const char*)x_lds + aSelf[gg] + dA);
      #pragma unroll
      for (int j = 0; j < 4; ++j) on[gg][j] = occ_lds[occSelf[gg] + dO + j];
    }

    const char* wmc = (const char*)wm_buf + cur * 8192;
    // B-frags per-tt (live 8 regs, shared by both columns' MFMAs); nested
    // MFMA pair with C = bmq broadcast (shared by both gg; D != C).
    #pragma unroll
    for (int tt = 0; tt < 4; ++tt) {
      const bf16x8 bS = *(const bf16x8*)(wmc + bOffS[tt]);
      const bf16x8 bN = *(const bf16x8*)(wmc + bOffN[tt]);
      const f32x4 bmq = {bmv[tt], bmv[tt], bmv[tt], bmv[tt]};
      #pragma unroll
      for (int gg = 0; gg < 2; ++gg) {
        const f32x4 acc = __builtin_amdgcn_mfma_f32_16x16x32_bf16(
            aN[gg], bN,
            __builtin_amdgcn_mfma_f32_16x16x32_bf16(aS[gg], bS, bmq, 0, 0, 0),
            0, 0, 0);
        #pragma unroll
        for (int j = 0; j < 4; ++j) {
          const float msg = fmaxf(acc[j], 0.0f);
          agg[gg][tt][j] = fmaf(msg, on[gg][j], agg[gg][tt][j]);
        }
      }
    }
    #pragma unroll
    for (int gg = 0; gg < 2; ++gg)
      #pragma unroll
      for (int j = 0; j < 4; ++j) den[gg][j] += on[gg][j];

    // barrier drains vmcnt(0) -> prefetched image i+1 is resident in cur^1
    __syncthreads();
    cur ^= 1;
  }

  // ---- agg /= (den + 1e-8) ----
  #pragma unroll
  for (int gg = 0; gg < 2; ++gg)
    #pragma unroll
    for (int j = 0; j < 4; ++j) {
      const float r = 1.0f / (den[gg][j] + 1e-8f);
      #pragma unroll
      for (int tt = 0; tt < 4; ++tt) agg[gg][tt][j] *= r;
    }

  // ---- update matmul: out = ([x|agg] @ Wu + bu) * occ_self ----
  char* scratch = (char*)wm_buf + w * 2048;  // per-wave 16 rows x 128B (aliases dbuf; private per wave)
  f32x4 buq[4];
  #pragma unroll
  for (int tt = 0; tt < 4; ++tt) {
    const float bv = bu[colIdx[tt]];
    buq[tt] = (f32x4){bv, bv, bv, bv};
  }

  #pragma unroll
  for (int gg = 0; gg < 2; ++gg) {
    // C-layout agg -> bf16 A-layout scratch (row-XOR swizzle); per-wave private,
    // wave-synchronous: no barrier needed (DS ops complete in order per wave)
    #pragma unroll
    for (int tt = 0; tt < 4; ++tt) {
      const int colhi = tt * 2 + ((lane >> 3) & 1);  // col>>3
      #pragma unroll
      for (int j = 0; j < 4; ++j) {
        const int row = q * 4 + j;
        const int bo = row * 128 + ((colhi ^ (row & 7)) << 4) + l7 * 2;
        *(unsigned short*)(scratch + bo) = f2bf(agg[gg][tt][j]);
      }
    }
    const bf16x8 ag0 = *(const bf16x8*)(scratch + m * 128 + ((q ^ (m & 7)) << 4));
    const bf16x8 ag1 = *(const bf16x8*)(scratch + m * 128 + (((4 + q) ^ (m & 7)) << 4));
    float os[4];
    #pragma unroll
    for (int j = 0; j < 4; ++j) os[j] = occ_lds[occSelf[gg] + j];
    // Wu fragments per-tt from global (L2-resident 16KB image); nested chain
    // with C = buq[tt] (shared across gg)
    #pragma unroll
    for (int tt = 0; tt < 4; ++tt) {
      const char* wc = (const char*)wu_img + colIdx[tt] * 256;
      const bf16x8 bux  = *(const bf16x8*)(wc + ((q ^ l7) << 4));        // Wu k 0..31 (x)
      const bf16x8 bua0 = *(const bf16x8*)(wc + (((4 + q) ^ l7) << 4));  // Wu k 32..63
      const bf16x8 bua1 = *(const bf16x8*)(wc + (((8 + q) ^ l7) << 4));  // Wu k 64..95
      const f32x4 acc = __builtin_amdgcn_mfma_f32_16x16x32_bf16(
          ag1, bua1,
          __builtin_amdgcn_mfma_f32_16x16x32_bf16(
              ag0, bua0,
              __builtin_amdgcn_mfma_f32_16x16x32_bf16(aS[gg], bux, buq[tt], 0, 0, 0),
              0, 0, 0),
          0, 0, 0);
      #pragma unroll
      for (int j = 0; j < 4; ++j) {
        out[(voxBase[gg] + q * 4 + j) * 64 + colIdx[tt]] = acc[j] * os[j];
      }
    }
  }
}

extern "C" void kernel_launch(void* const* d_in, const int* in_sizes, int n_in,
                              void* d_out, int out_size, void* d_ws, size_t ws_size,
                              hipStream_t stream) {
  const float* x   = (const float*)d_in[0];
  const float* occ = (const float*)d_in[1];
  const float* Wm  = (const float*)d_in[2];
  const float* bm  = (const float*)d_in[3];
  const float* Wu  = (const float*)d_in[4];
  const float* bu  = (const float*)d_in[5];
  float* out = (float*)d_out;

  unsigned short* wm_img = (unsigned short*)d_ws;        // 26*4096 ushort = 208 KB
  unsigned short* wu_img = wm_img + 26 * 4096;           // 8192 ushort   =  16 KB

  prep_weights<<<27, 256, 0, stream>>>(Wm, Wu, wm_img, wu_img);
  voxconv_main<<<2048, 512, 0, stream>>>(x, occ, bm, bu, wm_img, wu_img, out);
}